// Round 14
// baseline (282.657 us; speedup 1.0000x reference)
//
#include <hip/hip_runtime.h>

typedef unsigned short u16;
typedef unsigned int u32;
typedef unsigned long long u64;
typedef float f32x4 __attribute__((ext_vector_type(4)));
typedef short short8 __attribute__((ext_vector_type(8)));
typedef short bf16x4 __attribute__((ext_vector_type(4)));

#define BB 4
#define SS 2048
#define EE 1024
#define HH 16
#define DD 64
#define EPSV 1e-5f
#define LOG2E 1.4426950408889634f

__device__ __forceinline__ u16 f2b(float x) {
  u32 u = __float_as_uint(x);
  u32 r = (u + 0x7fffu + ((u >> 16) & 1u)) >> 16;
  return (u16)r;
}
__device__ __forceinline__ float b2f(u16 u) {
  return __uint_as_float(((u32)u) << 16);
}
__device__ __forceinline__ u32 cvtpk(float lo, float hi) {
  u32 r;
  asm("v_cvt_pk_bf16_f32 %0, %1, %2" : "=v"(r) : "v"(lo), "v"(hi));
  return r;
}
// raw v_exp_f32 (2^x) — avoids the __ocml_exp2_f32 libm call bloat
__device__ __forceinline__ float fexp2(float x) {
  float r;
  asm("v_exp_f32 %0, %1" : "=v"(r) : "v"(x));
  return r;
}
__device__ __forceinline__ void gload16(const void* g, void* l) {
  __builtin_amdgcn_global_load_lds(
      (const __attribute__((address_space(1))) u32*)g,
      (__attribute__((address_space(3))) u32*)l, 16, 0, 0);
}
// 16x16x16 bf16 MFMA with builtin-name fallback chain
__device__ __forceinline__ f32x4 mfma16(bf16x4 a, bf16x4 b, f32x4 c) {
#if __has_builtin(__builtin_amdgcn_mfma_f32_16x16x16_bf16)
  return __builtin_amdgcn_mfma_f32_16x16x16_bf16(a, b, c, 0, 0, 0);
#elif __has_builtin(__builtin_amdgcn_mfma_f32_16x16x16bf16_1k)
  return __builtin_amdgcn_mfma_f32_16x16x16bf16_1k(a, b, c, 0, 0, 0);
#else
  asm("v_mfma_f32_16x16x16_bf16 %0, %1, %2, %3"
      : "=v"(c) : "v"(a), "v"(b), "v"(c));
  return c;
#endif
}

// ---------------- LayerNorm: 1 block per row of 1024 fp32 ----------------
template<bool OUT_BF16>
__global__ __launch_bounds__(256) void ln_kernel(const float* __restrict__ x,
    const float* __restrict__ gamma, const float* __restrict__ beta,
    void* __restrict__ outp) {
  int row = blockIdx.x;
  int t = threadIdx.x;
  const float4* xr = (const float4*)(x + (size_t)row * EE);
  float4 v = xr[t];
  float s = v.x + v.y + v.z + v.w;
  #pragma unroll
  for (int o = 1; o < 64; o <<= 1) s += __shfl_xor(s, o);
  __shared__ float red[8];
  int wid = t >> 6;
  if ((t & 63) == 0) red[wid] = s;
  __syncthreads();
  float mean = (red[0] + red[1] + red[2] + red[3]) * (1.0f / EE);
  float d0 = v.x - mean, d1 = v.y - mean, d2 = v.z - mean, d3 = v.w - mean;
  float sq = d0 * d0 + d1 * d1 + d2 * d2 + d3 * d3;
  #pragma unroll
  for (int o = 1; o < 64; o <<= 1) sq += __shfl_xor(sq, o);
  if ((t & 63) == 0) red[4 + wid] = sq;
  __syncthreads();
  float var = (red[4] + red[5] + red[6] + red[7]) * (1.0f / EE);
  float rstd = rsqrtf(var + EPSV);
  float4 g = ((const float4*)gamma)[t];
  float4 be = ((const float4*)beta)[t];
  float o0 = d0 * rstd * g.x + be.x;
  float o1 = d1 * rstd * g.y + be.y;
  float o2 = d2 * rstd * g.z + be.z;
  float o3 = d3 * rstd * g.w + be.w;
  if (OUT_BF16) {
    ushort4 pk;
    pk.x = f2b(o0); pk.y = f2b(o1); pk.z = f2b(o2); pk.w = f2b(o3);
    *(ushort4*)((u16*)outp + (size_t)row * EE + t * 4) = pk;
  } else {
    ((float4*)((float*)outp + (size_t)row * EE))[t] = make_float4(o0, o1, o2, o3);
  }
}

// ---- fused preprocessing: LN(v), conv q/k, maskpack, wtrans x4; one launch ----
__global__ __launch_bounds__(256) void pre_kernel(
    const float* __restrict__ v, const float* __restrict__ gamma,
    const float* __restrict__ beta, u16* __restrict__ vn,
    const float* __restrict__ q, u16* __restrict__ qbf,
    const float* __restrict__ k, u16* __restrict__ kbf,
    const int* __restrict__ mask, u64* __restrict__ mp,
    const float* __restrict__ W1, const float* __restrict__ W2,
    const float* __restrict__ W3, const float* __restrict__ W4,
    u16* __restrict__ W1t, u16* __restrict__ W2t,
    u16* __restrict__ W3t, u16* __restrict__ W4t) {
  __shared__ float tile[32][33];
  __shared__ float red[8];
  int idx = blockIdx.x;
  int t = threadIdx.x;
  if (idx < 8192) {
    int row = idx;
    float4 vv = ((const float4*)(v + (size_t)row * EE))[t];
    float s = vv.x + vv.y + vv.z + vv.w;
    #pragma unroll
    for (int o = 1; o < 64; o <<= 1) s += __shfl_xor(s, o);
    int wid = t >> 6;
    if ((t & 63) == 0) red[wid] = s;
    __syncthreads();
    float mean = (red[0] + red[1] + red[2] + red[3]) * (1.0f / EE);
    float d0 = vv.x - mean, d1 = vv.y - mean, d2 = vv.z - mean, d3 = vv.w - mean;
    float sq = d0 * d0 + d1 * d1 + d2 * d2 + d3 * d3;
    #pragma unroll
    for (int o = 1; o < 64; o <<= 1) sq += __shfl_xor(sq, o);
    if ((t & 63) == 0) red[4 + wid] = sq;
    __syncthreads();
    float var = (red[4] + red[5] + red[6] + red[7]) * (1.0f / EE);
    float rstd = rsqrtf(var + EPSV);
    float4 g = ((const float4*)gamma)[t];
    float4 be = ((const float4*)beta)[t];
    ushort4 pk;
    pk.x = f2b(d0 * rstd * g.x + be.x);
    pk.y = f2b(d1 * rstd * g.y + be.y);
    pk.z = f2b(d2 * rstd * g.z + be.z);
    pk.w = f2b(d3 * rstd * g.w + be.w);
    *(ushort4*)(vn + (size_t)row * EE + t * 4) = pk;
  } else if (idx < 16384) {
    int i = idx - 8192;
    const float* x = (i >= 4096) ? k : q;
    u16* y = (i >= 4096) ? kbf : qbf;
    size_t off = ((size_t)(i & 4095) * 256 + t) * 8;
    float4 a = *(const float4*)(x + off);
    float4 c = *(const float4*)(x + off + 4);
    uint4 pk;
    pk.x = (u32)f2b(a.x) | ((u32)f2b(a.y) << 16);
    pk.y = (u32)f2b(a.z) | ((u32)f2b(a.w) << 16);
    pk.z = (u32)f2b(c.x) | ((u32)f2b(c.y) << 16);
    pk.w = (u32)f2b(c.z) | ((u32)f2b(c.w) << 16);
    *(uint4*)(y + off) = pk;
  } else if (idx < 32768) {
    int widx = idx - 16384;
    int wv = t >> 6, lane = t & 63;
    size_t base = (size_t)widx * 1024 + wv * 256;
    int v0 = mask[base + 0 * 64 + lane];
    int v1 = mask[base + 1 * 64 + lane];
    int v2 = mask[base + 2 * 64 + lane];
    int v3 = mask[base + 3 * 64 + lane];
    u64 b0 = __ballot(v0 != 0);
    u64 b1 = __ballot(v1 != 0);
    u64 b2 = __ballot(v2 != 0);
    u64 b3 = __ballot(v3 != 0);
    if (lane == 0) {
      u64* dst = &mp[base >> 6];
      dst[0] = b0; dst[1] = b1; dst[2] = b2; dst[3] = b3;
    }
  } else {
    int s = idx - 32768;
    int w = s >> 10, t2 = s & 1023;
    int kb = (t2 & 31) * 32, nb = (t2 >> 5) * 32;
    const float* W = (w == 0) ? W1 : (w == 1) ? W2 : (w == 2) ? W3 : W4;
    u16* Wt = (w == 0) ? W1t : (w == 1) ? W2t : (w == 2) ? W3t : W4t;
    int r = t >> 3, c = (t & 7) * 4;
    float4 vv = *(const float4*)&W[(size_t)(kb + r) * EE + nb + c];
    tile[r][c] = vv.x; tile[r][c + 1] = vv.y;
    tile[r][c + 2] = vv.z; tile[r][c + 3] = vv.w;
    __syncthreads();
    uint2 val;
    val.x = (u32)f2b(tile[c][r]) | ((u32)f2b(tile[c + 1][r]) << 16);
    val.y = (u32)f2b(tile[c + 2][r]) | ((u32)f2b(tile[c + 3][r]) << 16);
    *(uint2*)&Wt[(size_t)(nb + r) * EE + kb + c] = val;
  }
}

// ---------------- merged projection GEMM (q/k/v in one launch) ----------------
// XCD-local grid: launch (192, 8); panel id = blockIdx.x (so the 8 N-blocks of
// one A-panel have linear ids == panel (mod 8) -> same XCD L2 holds the panel).
__global__ __launch_bounds__(256) void gemm_proj(
    const u16* __restrict__ Aq, const u16* __restrict__ Ak,
    const u16* __restrict__ Av,
    const u16* __restrict__ W1t, const u16* __restrict__ W2t,
    const u16* __restrict__ W3t,
    const float* __restrict__ b1, const float* __restrict__ b2,
    const float* __restrict__ b3,
    u16* __restrict__ qh, u16* __restrict__ kh, u16* __restrict__ vt,
    int yoff) {
  constexpr int N = 1024, K = 1024;
  __shared__ u16 Al[128 * 32];
  __shared__ u16 Bl[128 * 32];
  int y = blockIdx.x + yoff;
  int sel = y >> 6, my = y & 63;
  const u16* Ap = (sel == 0) ? Aq : (sel == 1) ? Ak : Av;
  const u16* Bt = (sel == 0) ? W1t : (sel == 1) ? W2t : W3t;
  const float* bias = (sel == 0) ? b1 : (sel == 1) ? b2 : b3;
  u16* Cp = (sel == 0) ? qh : (sel == 1) ? kh : vt;
  float oscale = (sel == 0) ? LOG2E : 1.0f;

  int t = threadIdx.x;
  int lane = t & 63, wid = t >> 6;
  int mb = my * 128, nb = blockIdx.y * 128;
  int wm = (wid >> 1) * 64, wn = (wid & 1) * 64;
  int l15 = lane & 15, lg = lane >> 4;

  int srow = lane >> 2;
  int schunk = (lane & 3) ^ (srow & 3);
  const u16* Ag = Ap + (size_t)(mb + wid * 32 + srow) * K + schunk * 8;
  const u16* Bg = Bt + (size_t)(nb + wid * 32 + srow) * K + schunk * 8;
  u16* Alw0 = &Al[(wid * 32) * 32];
  u16* Alw1 = &Al[(wid * 32 + 16) * 32];
  u16* Blw0 = &Bl[(wid * 32) * 32];
  u16* Blw1 = &Bl[(wid * 32 + 16) * 32];
  int ca = (lg ^ (l15 & 3)) * 8;

  f32x4 acc[4][4] = {};
  for (int kt = 0; kt < K; kt += 32) {
    gload16(Ag + kt, Alw0);
    gload16(Ag + kt + (size_t)16 * K, Alw1);
    gload16(Bg + kt, Blw0);
    gload16(Bg + kt + (size_t)16 * K, Blw1);
    __syncthreads();
    short8 af[4], bfv[4];
    #pragma unroll
    for (int mf = 0; mf < 4; mf++)
      af[mf] = *(const short8*)&Al[(wm + mf * 16 + l15) * 32 + ca];
    #pragma unroll
    for (int nf = 0; nf < 4; nf++)
      bfv[nf] = *(const short8*)&Bl[(wn + nf * 16 + l15) * 32 + ca];
    #pragma unroll
    for (int mf = 0; mf < 4; mf++)
      #pragma unroll
      for (int nf = 0; nf < 4; nf++)
        acc[mf][nf] = __builtin_amdgcn_mfma_f32_16x16x32_bf16(af[mf], bfv[nf], acc[mf][nf], 0, 0, 0);
    __syncthreads();
  }
  float bv[4];
  #pragma unroll
  for (int nf = 0; nf < 4; nf++) bv[nf] = bias[nb + wn + nf * 16 + l15];
  if (sel == 2) {
    #pragma unroll
    for (int mf = 0; mf < 4; mf++) {
      int m0 = mb + wm + mf * 16 + lg * 4;
      int bq = m0 >> 11, s0 = m0 & 2047;
      #pragma unroll
      for (int nf = 0; nf < 4; nf++) {
        int n = nb + wn + nf * 16 + l15;
        int h = n >> 6, d = n & 63;
        ushort4 pk;
        pk.x = f2b(acc[mf][nf][0] + bv[nf]);
        pk.y = f2b(acc[mf][nf][1] + bv[nf]);
        pk.z = f2b(acc[mf][nf][2] + bv[nf]);
        pk.w = f2b(acc[mf][nf][3] + bv[nf]);
        *(ushort4*)&vt[((size_t)((bq * HH + h) * DD + d)) * SS + s0] = pk;
      }
    }
  } else {
    #pragma unroll
    for (int mf = 0; mf < 4; mf++) {
      #pragma unroll
      for (int r = 0; r < 4; r++) {
        int m = mb + wm + mf * 16 + lg * 4 + r;
        #pragma unroll
        for (int nf = 0; nf < 4; nf++) {
          int n = nb + wn + nf * 16 + l15;
          Cp[(size_t)m * N + n] = f2b((acc[mf][nf][r] + bv[nf]) * oscale);
        }
      }
    }
  }
}

// ---------------- output GEMM: fp32 C = A@W4t^T + b4 + residual ----------------
// XCD-local grid: launch (64, 8); panel id = blockIdx.x.
__global__ __launch_bounds__(256) void gemm_out(const u16* __restrict__ Ap,
    const u16* __restrict__ Bt, const float* __restrict__ bias,
    const u16* __restrict__ resid, float* __restrict__ Cp) {
  constexpr int N = 1024, K = 1024;
  __shared__ u16 Al[128 * 32];
  __shared__ u16 Bl[128 * 32];
  int t = threadIdx.x;
  int lane = t & 63, wid = t >> 6;
  int mb = blockIdx.x * 128, nb = blockIdx.y * 128;
  int wm = (wid >> 1) * 64, wn = (wid & 1) * 64;
  int l15 = lane & 15, lg = lane >> 4;
  int srow = lane >> 2;
  int schunk = (lane & 3) ^ (srow & 3);
  const u16* Ag = Ap + (size_t)(mb + wid * 32 + srow) * K + schunk * 8;
  const u16* Bg = Bt + (size_t)(nb + wid * 32 + srow) * K + schunk * 8;
  u16* Alw0 = &Al[(wid * 32) * 32];
  u16* Alw1 = &Al[(wid * 32 + 16) * 32];
  u16* Blw0 = &Bl[(wid * 32) * 32];
  u16* Blw1 = &Bl[(wid * 32 + 16) * 32];
  int ca = (lg ^ (l15 & 3)) * 8;
  f32x4 acc[4][4] = {};
  for (int kt = 0; kt < K; kt += 32) {
    gload16(Ag + kt, Alw0);
    gload16(Ag + kt + (size_t)16 * K, Alw1);
    gload16(Bg + kt, Blw0);
    gload16(Bg + kt + (size_t)16 * K, Blw1);
    __syncthreads();
    short8 af[4], bfv[4];
    #pragma unroll
    for (int mf = 0; mf < 4; mf++)
      af[mf] = *(const short8*)&Al[(wm + mf * 16 + l15) * 32 + ca];
    #pragma unroll
    for (int nf = 0; nf < 4; nf++)
      bfv[nf] = *(const short8*)&Bl[(wn + nf * 16 + l15) * 32 + ca];
    #pragma unroll
    for (int mf = 0; mf < 4; mf++)
      #pragma unroll
      for (int nf = 0; nf < 4; nf++)
        acc[mf][nf] = __builtin_amdgcn_mfma_f32_16x16x32_bf16(af[mf], bfv[nf], acc[mf][nf], 0, 0, 0);
    __syncthreads();
  }
  float bv[4];
  #pragma unroll
  for (int nf = 0; nf < 4; nf++) bv[nf] = bias[nb + wn + nf * 16 + l15];
  #pragma unroll
  for (int mf = 0; mf < 4; mf++) {
    #pragma unroll
    for (int r = 0; r < 4; r++) {
      int m = mb + wm + mf * 16 + lg * 4 + r;
      #pragma unroll
      for (int nf = 0; nf < 4; nf++) {
        int n = nb + wn + nf * 16 + l15;
        float rv = b2f(resid[(size_t)m * N + n]);
        Cp[(size_t)m * N + n] = acc[mf][nf][r] + bv[nf] + rv;
      }
    }
  }
}

// ---------------- flash attention, 2 Q-tiles per block, XCD-local, dbuf LDS ----------------
// grid: (B*H, S/128): all 16 qt-blocks of one (b,h) share XCD bh%8's L2 K/V.
// Double-buffered K/V (33 KB LDS, still 4 blocks/CU at this grid): prefetch regs
// -> QK from cur -> commit regs to cur^1 -> PV from cur -> ONE barrier per tile.
// 4 waves x 2 q-sets; double-swapped MFMA; fixed-bound softmax; LUT mask.
__global__ __launch_bounds__(256) void attn_kernel(const u16* __restrict__ qh,
    const u16* __restrict__ kh, const u16* __restrict__ vt,
    const u64* __restrict__ mp, u16* __restrict__ outp) {
  __shared__ u16 Kl[2][64 * 64];
  __shared__ u16 Vl[2][64 * 64];
  __shared__ u64 lutq[16];
  int t = threadIdx.x, lane = t & 63, wid = t >> 6;
  int bh = blockIdx.x, b = bh >> 4, h = bh & 15;
  int qt = blockIdx.y;
  int l15 = lane & 15, lg = lane >> 4;

  if (t < 16) {
    u32 n = t;
    u32 w0 = ((n & 1) ? 0u : 0xFFFFu) | ((n & 2) ? 0u : 0xFFFF0000u);
    u32 w1 = ((n & 4) ? 0u : 0xFFFFu) | ((n & 8) ? 0u : 0xFFFF0000u);
    lutq[n] = (u64)w0 | ((u64)w1 << 32);
  }

  int qrow0 = qt * 128 + wid * 16 + l15;
  int qrow1 = qrow0 + 64;
  const u16* qbase0 = qh + ((size_t)(b * SS + qrow0)) * EE + h * DD;
  const u16* qbase1 = qh + ((size_t)(b * SS + qrow1)) * EE + h * DD;
  short8 qa0 = *(const short8*)(qbase0 + lg * 8);
  short8 qa1 = *(const short8*)(qbase0 + 32 + lg * 8);
  short8 qb0 = *(const short8*)(qbase1 + lg * 8);
  short8 qb1 = *(const short8*)(qbase1 + 32 + lg * 8);
  const u64* mrow0 = mp + (size_t)(b * SS + qrow0) * (SS / 64);
  const u64* mrow1 = mp + (size_t)(b * SS + qrow1) * (SS / 64);

  bf16x4 onesv;
  #pragma unroll
  for (int i = 0; i < 4; i++) onesv[i] = (short)0x3F80;  // bf16 1.0

  int r0 = wid * 16 + (lane >> 3);
  int r1 = r0 + 8;
  int cc = lane & 7;
  int wk0 = r0 * 64 + ((cc ^ (r0 & 7)) * 8);
  int wk1 = r1 * 64 + ((cc ^ (r1 & 7)) * 8);
  const u16* kgb = kh + ((size_t)b * SS) * EE + h * DD;
  const u16* vgb = vt + ((size_t)bh * DD) * SS;

  int ck0 = (lg ^ (l15 & 7)) * 8;
  int ck1 = ((4 + lg) ^ (l15 & 7)) * 8;
  int vbase0 = l15 * 64 + ((lg >> 1) ^ (l15 & 7)) * 8 + (lg & 1) * 4;

  f32x4 Oa[4] = {}, Ob[4] = {};
  f32x4 asuma = {}, asumb = {};
  constexpr int NT = SS / 64;

  // preload tile 0, commit to buf 0
  uint4 sk0 = *(const uint4*)(kgb + (size_t)r0 * EE + cc * 8);
  uint4 sk1 = *(const uint4*)(kgb + (size_t)r1 * EE + cc * 8);
  uint4 sv0 = *(const uint4*)(vgb + (size_t)r0 * SS + cc * 8);
  uint4 sv1 = *(const uint4*)(vgb + (size_t)r1 * SS + cc * 8);
  *(uint4*)&Kl[0][wk0] = sk0;
  *(uint4*)&Kl[0][wk1] = sk1;
  *(uint4*)&Vl[0][wk0] = sv0;
  *(uint4*)&Vl[0][wk1] = sv1;
  const u16* kp0 = kgb + (size_t)(64 + r0) * EE + cc * 8;
  const u16* kp1 = kgb + (size_t)(64 + r1) * EE + cc * 8;
  const u16* vp0 = vgb + (size_t)r0 * SS + 64 + cc * 8;
  const u16* vp1 = vgb + (size_t)r1 * SS + 64 + cc * 8;
  u64 mwa = mrow0[0];
  u64 mwb = mrow1[0];
  __syncthreads();

  int cur = 0;
  for (int kt = 0; kt < NT; ++kt) {
    // prefetch next tile into regs (last iteration reads 1 past — in-bounds ws)
    sk0 = *(const uint4*)kp0; kp0 += 64 * EE;
    sk1 = *(const uint4*)kp1; kp1 += 64 * EE;
    sv0 = *(const uint4*)vp0; vp0 += 64;
    sv1 = *(const uint4*)vp1; vp1 += 64;
    u64 mwan = mrow0[kt + 1];
    u64 mwbn = mrow1[kt + 1];

    const u16* Kc = Kl[cur];
    const u16* Vc = Vl[cur];

    // mask nibble decode + LUT pattern reads, both q-sets
    u32 mloa = (u32)(mwa >> (lg * 4));
    u32 mhia = (u32)(mwa >> 32 >> (lg * 4));
    u32 mlob = (u32)(mwb >> (lg * 4));
    u32 mhib = (u32)(mwb >> 32 >> (lg * 4));
    uint2 pata[4], patb[4];
    pata[0] = *(uint2*)&lutq[mloa & 15u];
    pata[1] = *(uint2*)&lutq[(mloa >> 16) & 15u];
    pata[2] = *(uint2*)&lutq[mhia & 15u];
    pata[3] = *(uint2*)&lutq[(mhia >> 16) & 15u];
    patb[0] = *(uint2*)&lutq[mlob & 15u];
    patb[1] = *(uint2*)&lutq[(mlob >> 16) & 15u];
    patb[2] = *(uint2*)&lutq[mhib & 15u];
    patb[3] = *(uint2*)&lutq[(mhib >> 16) & 15u];

    // QK^T swapped, both q-sets off the SAME K fragments
    f32x4 sca[4], scb[4];
    #pragma unroll
    for (int nf = 0; nf < 4; nf++) {
      int row = nf * 16 + l15;
      short8 k0 = *(const short8*)&Kc[row * 64 + ck0];
      short8 k1 = *(const short8*)&Kc[row * 64 + ck1];
      f32x4 za = {}, zb = {};
      za = __builtin_amdgcn_mfma_f32_16x16x32_bf16(k0, qa0, za, 0, 0, 0);
      za = __builtin_amdgcn_mfma_f32_16x16x32_bf16(k1, qa1, za, 0, 0, 0);
      zb = __builtin_amdgcn_mfma_f32_16x16x32_bf16(k0, qb0, zb, 0, 0, 0);
      zb = __builtin_amdgcn_mfma_f32_16x16x32_bf16(k1, qb1, zb, 0, 0, 0);
      sca[nf] = za;
      scb[nf] = zb;
    }

    // P = exp2(sc)
    #pragma unroll
    for (int nf = 0; nf < 4; nf++) {
      #pragma unroll
      for (int r = 0; r < 4; r++) {
        sca[nf][r] = fexp2(sca[nf][r]);
        scb[nf][r] = fexp2(scb[nf][r]);
      }
    }

    // commit prefetched tile to the OTHER buffer (consumed next iteration;
    // its previous readers finished at last iteration's barrier)
    {
      u16* Kn = Kl[cur ^ 1];
      u16* Vn = Vl[cur ^ 1];
      *(uint4*)&Kn[wk0] = sk0;
      *(uint4*)&Kn[wk1] = sk1;
      *(uint4*)&Vn[wk0] = sv0;
      *(uint4*)&Vn[wk1] = sv1;
    }

    // pack + mask-AND + asum + PV, sharing V fragments between q-sets
    #pragma unroll
    for (int nf = 0; nf < 4; nf++) {
      bf16x4 pba, pbb;
      ((u32*)&pba)[0] = cvtpk(sca[nf][0], sca[nf][1]) & pata[nf].x;
      ((u32*)&pba)[1] = cvtpk(sca[nf][2], sca[nf][3]) & pata[nf].y;
      ((u32*)&pbb)[0] = cvtpk(scb[nf][0], scb[nf][1]) & patb[nf].x;
      ((u32*)&pbb)[1] = cvtpk(scb[nf][2], scb[nf][3]) & patb[nf].y;
      asuma = mfma16(onesv, pba, asuma);
      asumb = mfma16(onesv, pbb, asumb);
      int vo = vbase0 ^ (nf * 16);
      #pragma unroll
      for (int df = 0; df < 4; df++) {
        bf16x4 vf = *(const bf16x4*)&Vc[vo + df * 1024];
        Oa[df] = mfma16(vf, pba, Oa[df]);
        Ob[df] = mfma16(vf, pbb, Ob[df]);
      }
    }
    mwa = mwan;
    mwb = mwbn;
    __syncthreads();
    cur ^= 1;
  }

  float inva = 1.0f / asuma[0];
  float invb = 1.0f / asumb[0];
  u16* ob0 = outp + ((size_t)(b * SS + qrow0)) * EE + h * DD + lg * 4;
  u16* ob1 = outp + ((size_t)(b * SS + qrow1)) * EE + h * DD + lg * 4;
  #pragma unroll
  for (int df = 0; df < 4; df++) {
    ushort4 pka, pkb;
    pka.x = f2b(Oa[df][0] * inva);
    pka.y = f2b(Oa[df][1] * inva);
    pka.z = f2b(Oa[df][2] * inva);
    pka.w = f2b(Oa[df][3] * inva);
    pkb.x = f2b(Ob[df][0] * invb);
    pkb.y = f2b(Ob[df][1] * invb);
    pkb.z = f2b(Ob[df][2] * invb);
    pkb.w = f2b(Ob[df][3] * invb);
    *(ushort4*)(ob0 + df * 16) = pka;
    *(ushort4*)(ob1 + df * 16) = pkb;
  }
}

extern "C" void kernel_launch(void* const* d_in, const int* in_sizes, int n_in,
                              void* d_out, int out_size, void* d_ws, size_t ws_size,
                              hipStream_t stream) {
  (void)in_sizes; (void)n_in; (void)out_size;
  const float* q    = (const float*)d_in[0];
  const float* k    = (const float*)d_in[1];
  const float* v    = (const float*)d_in[2];
  const int*   mask = (const int*)d_in[3];
  const float* W1   = (const float*)d_in[4];
  const float* b1   = (const float*)d_in[5];
  const float* W2   = (const float*)d_in[6];
  const float* b2   = (const float*)d_in[7];
  const float* W3   = (const float*)d_in[8];
  const float* b3   = (const float*)d_in[9];
  const float* W4   = (const float*)d_in[10];
  const float* b4   = (const float*)d_in[11];
  const float* gamma = (const float*)d_in[12];
  const float* beta  = (const float*)d_in[13];
  float* out = (float*)d_out;
  char* ws = (char*)d_ws;
  const size_t MB = 1024 * 1024;
  u16* qh  = (u16*)(ws + 0 * MB);
  u16* kh  = (u16*)(ws + 16 * MB);
  u16* vt  = (u16*)(ws + 32 * MB);   // early (fallback): kbf; later: V^T
  u16* ao  = (u16*)(ws + 48 * MB);   // early: qbf; later: attn out
  u16* vn  = (u16*)(ws + 64 * MB);
  u16* W1t = (u16*)(ws + 80 * MB);
  u16* W2t = (u16*)(ws + 82 * MB);
  u16* W3t = (u16*)(ws + 84 * MB);
  u16* W4t = (u16*)(ws + 86 * MB);
  u64* mp  = (u64*)(ws + 88 * MB);
  float* tmp = (float*)(ws + 0 * MB);  // overlays qh+kh (dead by then)
  u16* qbf = ao;

  bool ws_ok = ws_size >= 107 * MB;
  u16* kbf = ws_ok ? (u16*)(ws + 90 * MB) : vt;

  pre_kernel<<<36864, 256, 0, stream>>>(v, gamma, beta, vn, q, qbf, k, kbf,
                                        mask, mp, W1, W2, W3, W4,
                                        W1t, W2t, W3t, W4t);
  if (ws_ok) {
    gemm_proj<<<dim3(192, 8), 256, 0, stream>>>(qbf, kbf, vn, W1t, W2t, W3t,
                                                b1, b2, b3, qh, kh, vt, 0);
  } else {
    gemm_proj<<<dim3(128, 8), 256, 0, stream>>>(qbf, kbf, vn, W1t, W2t, W3t,
                                                b1, b2, b3, qh, kh, vt, 0);
    gemm_proj<<<dim3(64, 8), 256, 0, stream>>>(qbf, kbf, vn, W1t, W2t, W3t,
                                               b1, b2, b3, qh, kh, vt, 128);
  }
  attn_kernel<<<dim3(64, 16), 256, 0, stream>>>(qh, kh, vt, mp, ao);
  gemm_out<<<dim3(64, 8), 256, 0, stream>>>(ao, W4t, b4, vn, tmp);
  ln_kernel<false><<<8192, 256, 0, stream>>>(tmp, gamma, beta, out);
}

// Round 15
// 271.814 us; speedup vs baseline: 1.0399x; 1.0399x over previous
//
#include <hip/hip_runtime.h>

typedef unsigned short u16;
typedef unsigned int u32;
typedef unsigned long long u64;
typedef float f32x4 __attribute__((ext_vector_type(4)));
typedef short short8 __attribute__((ext_vector_type(8)));
typedef short bf16x4 __attribute__((ext_vector_type(4)));

#define BB 4
#define SS 2048
#define EE 1024
#define HH 16
#define DD 64
#define EPSV 1e-5f
#define LOG2E 1.4426950408889634f

__device__ __forceinline__ u16 f2b(float x) {
  u32 u = __float_as_uint(x);
  u32 r = (u + 0x7fffu + ((u >> 16) & 1u)) >> 16;
  return (u16)r;
}
__device__ __forceinline__ float b2f(u16 u) {
  return __uint_as_float(((u32)u) << 16);
}
__device__ __forceinline__ u32 cvtpk(float lo, float hi) {
  u32 r;
  asm("v_cvt_pk_bf16_f32 %0, %1, %2" : "=v"(r) : "v"(lo), "v"(hi));
  return r;
}
// raw v_exp_f32 (2^x) — avoids the __ocml_exp2_f32 libm call bloat
__device__ __forceinline__ float fexp2(float x) {
  float r;
  asm("v_exp_f32 %0, %1" : "=v"(r) : "v"(x));
  return r;
}
__device__ __forceinline__ void gload16(const void* g, void* l) {
  __builtin_amdgcn_global_load_lds(
      (const __attribute__((address_space(1))) u32*)g,
      (__attribute__((address_space(3))) u32*)l, 16, 0, 0);
}
// 16x16x16 bf16 MFMA with builtin-name fallback chain
__device__ __forceinline__ f32x4 mfma16(bf16x4 a, bf16x4 b, f32x4 c) {
#if __has_builtin(__builtin_amdgcn_mfma_f32_16x16x16_bf16)
  return __builtin_amdgcn_mfma_f32_16x16x16_bf16(a, b, c, 0, 0, 0);
#elif __has_builtin(__builtin_amdgcn_mfma_f32_16x16x16bf16_1k)
  return __builtin_amdgcn_mfma_f32_16x16x16bf16_1k(a, b, c, 0, 0, 0);
#else
  asm("v_mfma_f32_16x16x16_bf16 %0, %1, %2, %3"
      : "=v"(c) : "v"(a), "v"(b), "v"(c));
  return c;
#endif
}

// ---------------- LayerNorm: 1 block per row of 1024 fp32 ----------------
template<bool OUT_BF16>
__global__ __launch_bounds__(256) void ln_kernel(const float* __restrict__ x,
    const float* __restrict__ gamma, const float* __restrict__ beta,
    void* __restrict__ outp) {
  int row = blockIdx.x;
  int t = threadIdx.x;
  const float4* xr = (const float4*)(x + (size_t)row * EE);
  float4 v = xr[t];
  float s = v.x + v.y + v.z + v.w;
  #pragma unroll
  for (int o = 1; o < 64; o <<= 1) s += __shfl_xor(s, o);
  __shared__ float red[8];
  int wid = t >> 6;
  if ((t & 63) == 0) red[wid] = s;
  __syncthreads();
  float mean = (red[0] + red[1] + red[2] + red[3]) * (1.0f / EE);
  float d0 = v.x - mean, d1 = v.y - mean, d2 = v.z - mean, d3 = v.w - mean;
  float sq = d0 * d0 + d1 * d1 + d2 * d2 + d3 * d3;
  #pragma unroll
  for (int o = 1; o < 64; o <<= 1) sq += __shfl_xor(sq, o);
  if ((t & 63) == 0) red[4 + wid] = sq;
  __syncthreads();
  float var = (red[4] + red[5] + red[6] + red[7]) * (1.0f / EE);
  float rstd = rsqrtf(var + EPSV);
  float4 g = ((const float4*)gamma)[t];
  float4 be = ((const float4*)beta)[t];
  float o0 = d0 * rstd * g.x + be.x;
  float o1 = d1 * rstd * g.y + be.y;
  float o2 = d2 * rstd * g.z + be.z;
  float o3 = d3 * rstd * g.w + be.w;
  if (OUT_BF16) {
    ushort4 pk;
    pk.x = f2b(o0); pk.y = f2b(o1); pk.z = f2b(o2); pk.w = f2b(o3);
    *(ushort4*)((u16*)outp + (size_t)row * EE + t * 4) = pk;
  } else {
    ((float4*)((float*)outp + (size_t)row * EE))[t] = make_float4(o0, o1, o2, o3);
  }
}

// ---- fused preprocessing: LN(v), conv q/k, maskpack, wtrans x4; one launch ----
__global__ __launch_bounds__(256) void pre_kernel(
    const float* __restrict__ v, const float* __restrict__ gamma,
    const float* __restrict__ beta, u16* __restrict__ vn,
    const float* __restrict__ q, u16* __restrict__ qbf,
    const float* __restrict__ k, u16* __restrict__ kbf,
    const int* __restrict__ mask, u64* __restrict__ mp,
    const float* __restrict__ W1, const float* __restrict__ W2,
    const float* __restrict__ W3, const float* __restrict__ W4,
    u16* __restrict__ W1t, u16* __restrict__ W2t,
    u16* __restrict__ W3t, u16* __restrict__ W4t) {
  __shared__ float tile[32][33];
  __shared__ float red[8];
  int idx = blockIdx.x;
  int t = threadIdx.x;
  if (idx < 8192) {
    int row = idx;
    float4 vv = ((const float4*)(v + (size_t)row * EE))[t];
    float s = vv.x + vv.y + vv.z + vv.w;
    #pragma unroll
    for (int o = 1; o < 64; o <<= 1) s += __shfl_xor(s, o);
    int wid = t >> 6;
    if ((t & 63) == 0) red[wid] = s;
    __syncthreads();
    float mean = (red[0] + red[1] + red[2] + red[3]) * (1.0f / EE);
    float d0 = vv.x - mean, d1 = vv.y - mean, d2 = vv.z - mean, d3 = vv.w - mean;
    float sq = d0 * d0 + d1 * d1 + d2 * d2 + d3 * d3;
    #pragma unroll
    for (int o = 1; o < 64; o <<= 1) sq += __shfl_xor(sq, o);
    if ((t & 63) == 0) red[4 + wid] = sq;
    __syncthreads();
    float var = (red[4] + red[5] + red[6] + red[7]) * (1.0f / EE);
    float rstd = rsqrtf(var + EPSV);
    float4 g = ((const float4*)gamma)[t];
    float4 be = ((const float4*)beta)[t];
    ushort4 pk;
    pk.x = f2b(d0 * rstd * g.x + be.x);
    pk.y = f2b(d1 * rstd * g.y + be.y);
    pk.z = f2b(d2 * rstd * g.z + be.z);
    pk.w = f2b(d3 * rstd * g.w + be.w);
    *(ushort4*)(vn + (size_t)row * EE + t * 4) = pk;
  } else if (idx < 16384) {
    int i = idx - 8192;
    const float* x = (i >= 4096) ? k : q;
    u16* y = (i >= 4096) ? kbf : qbf;
    size_t off = ((size_t)(i & 4095) * 256 + t) * 8;
    float4 a = *(const float4*)(x + off);
    float4 c = *(const float4*)(x + off + 4);
    uint4 pk;
    pk.x = (u32)f2b(a.x) | ((u32)f2b(a.y) << 16);
    pk.y = (u32)f2b(a.z) | ((u32)f2b(a.w) << 16);
    pk.z = (u32)f2b(c.x) | ((u32)f2b(c.y) << 16);
    pk.w = (u32)f2b(c.z) | ((u32)f2b(c.w) << 16);
    *(uint4*)(y + off) = pk;
  } else if (idx < 32768) {
    int widx = idx - 16384;
    int wv = t >> 6, lane = t & 63;
    size_t base = (size_t)widx * 1024 + wv * 256;
    int v0 = mask[base + 0 * 64 + lane];
    int v1 = mask[base + 1 * 64 + lane];
    int v2 = mask[base + 2 * 64 + lane];
    int v3 = mask[base + 3 * 64 + lane];
    u64 b0 = __ballot(v0 != 0);
    u64 b1 = __ballot(v1 != 0);
    u64 b2 = __ballot(v2 != 0);
    u64 b3 = __ballot(v3 != 0);
    if (lane == 0) {
      u64* dst = &mp[base >> 6];
      dst[0] = b0; dst[1] = b1; dst[2] = b2; dst[3] = b3;
    }
  } else {
    int s = idx - 32768;
    int w = s >> 10, t2 = s & 1023;
    int kb = (t2 & 31) * 32, nb = (t2 >> 5) * 32;
    const float* W = (w == 0) ? W1 : (w == 1) ? W2 : (w == 2) ? W3 : W4;
    u16* Wt = (w == 0) ? W1t : (w == 1) ? W2t : (w == 2) ? W3t : W4t;
    int r = t >> 3, c = (t & 7) * 4;
    float4 vv = *(const float4*)&W[(size_t)(kb + r) * EE + nb + c];
    tile[r][c] = vv.x; tile[r][c + 1] = vv.y;
    tile[r][c + 2] = vv.z; tile[r][c + 3] = vv.w;
    __syncthreads();
    uint2 val;
    val.x = (u32)f2b(tile[c][r]) | ((u32)f2b(tile[c + 1][r]) << 16);
    val.y = (u32)f2b(tile[c + 2][r]) | ((u32)f2b(tile[c + 3][r]) << 16);
    *(uint2*)&Wt[(size_t)(nb + r) * EE + kb + c] = val;
  }
}

// ---------------- merged projection GEMM (q/k/v in one launch) ----------------
// XCD-local grid: launch (192, 8); panel id = blockIdx.x (so the 8 N-blocks of
// one A-panel have linear ids == panel (mod 8) -> same XCD L2 holds the panel).
__global__ __launch_bounds__(256) void gemm_proj(
    const u16* __restrict__ Aq, const u16* __restrict__ Ak,
    const u16* __restrict__ Av,
    const u16* __restrict__ W1t, const u16* __restrict__ W2t,
    const u16* __restrict__ W3t,
    const float* __restrict__ b1, const float* __restrict__ b2,
    const float* __restrict__ b3,
    u16* __restrict__ qh, u16* __restrict__ kh, u16* __restrict__ vt,
    int yoff) {
  constexpr int N = 1024, K = 1024;
  __shared__ u16 Al[128 * 32];
  __shared__ u16 Bl[128 * 32];
  int y = blockIdx.x + yoff;
  int sel = y >> 6, my = y & 63;
  const u16* Ap = (sel == 0) ? Aq : (sel == 1) ? Ak : Av;
  const u16* Bt = (sel == 0) ? W1t : (sel == 1) ? W2t : W3t;
  const float* bias = (sel == 0) ? b1 : (sel == 1) ? b2 : b3;
  u16* Cp = (sel == 0) ? qh : (sel == 1) ? kh : vt;
  float oscale = (sel == 0) ? LOG2E : 1.0f;

  int t = threadIdx.x;
  int lane = t & 63, wid = t >> 6;
  int mb = my * 128, nb = blockIdx.y * 128;
  int wm = (wid >> 1) * 64, wn = (wid & 1) * 64;
  int l15 = lane & 15, lg = lane >> 4;

  int srow = lane >> 2;
  int schunk = (lane & 3) ^ (srow & 3);
  const u16* Ag = Ap + (size_t)(mb + wid * 32 + srow) * K + schunk * 8;
  const u16* Bg = Bt + (size_t)(nb + wid * 32 + srow) * K + schunk * 8;
  u16* Alw0 = &Al[(wid * 32) * 32];
  u16* Alw1 = &Al[(wid * 32 + 16) * 32];
  u16* Blw0 = &Bl[(wid * 32) * 32];
  u16* Blw1 = &Bl[(wid * 32 + 16) * 32];
  int ca = (lg ^ (l15 & 3)) * 8;

  f32x4 acc[4][4] = {};
  for (int kt = 0; kt < K; kt += 32) {
    gload16(Ag + kt, Alw0);
    gload16(Ag + kt + (size_t)16 * K, Alw1);
    gload16(Bg + kt, Blw0);
    gload16(Bg + kt + (size_t)16 * K, Blw1);
    __syncthreads();
    short8 af[4], bfv[4];
    #pragma unroll
    for (int mf = 0; mf < 4; mf++)
      af[mf] = *(const short8*)&Al[(wm + mf * 16 + l15) * 32 + ca];
    #pragma unroll
    for (int nf = 0; nf < 4; nf++)
      bfv[nf] = *(const short8*)&Bl[(wn + nf * 16 + l15) * 32 + ca];
    #pragma unroll
    for (int mf = 0; mf < 4; mf++)
      #pragma unroll
      for (int nf = 0; nf < 4; nf++)
        acc[mf][nf] = __builtin_amdgcn_mfma_f32_16x16x32_bf16(af[mf], bfv[nf], acc[mf][nf], 0, 0, 0);
    __syncthreads();
  }
  float bv[4];
  #pragma unroll
  for (int nf = 0; nf < 4; nf++) bv[nf] = bias[nb + wn + nf * 16 + l15];
  if (sel == 2) {
    #pragma unroll
    for (int mf = 0; mf < 4; mf++) {
      int m0 = mb + wm + mf * 16 + lg * 4;
      int bq = m0 >> 11, s0 = m0 & 2047;
      #pragma unroll
      for (int nf = 0; nf < 4; nf++) {
        int n = nb + wn + nf * 16 + l15;
        int h = n >> 6, d = n & 63;
        ushort4 pk;
        pk.x = f2b(acc[mf][nf][0] + bv[nf]);
        pk.y = f2b(acc[mf][nf][1] + bv[nf]);
        pk.z = f2b(acc[mf][nf][2] + bv[nf]);
        pk.w = f2b(acc[mf][nf][3] + bv[nf]);
        *(ushort4*)&vt[((size_t)((bq * HH + h) * DD + d)) * SS + s0] = pk;
      }
    }
  } else {
    #pragma unroll
    for (int mf = 0; mf < 4; mf++) {
      #pragma unroll
      for (int r = 0; r < 4; r++) {
        int m = mb + wm + mf * 16 + lg * 4 + r;
        #pragma unroll
        for (int nf = 0; nf < 4; nf++) {
          int n = nb + wn + nf * 16 + l15;
          Cp[(size_t)m * N + n] = f2b((acc[mf][nf][r] + bv[nf]) * oscale);
        }
      }
    }
  }
}

// ---------------- output GEMM: fp32 C = A@W4t^T + b4 + residual ----------------
// XCD-local grid: launch (64, 8); panel id = blockIdx.x.
__global__ __launch_bounds__(256) void gemm_out(const u16* __restrict__ Ap,
    const u16* __restrict__ Bt, const float* __restrict__ bias,
    const u16* __restrict__ resid, float* __restrict__ Cp) {
  constexpr int N = 1024, K = 1024;
  __shared__ u16 Al[128 * 32];
  __shared__ u16 Bl[128 * 32];
  int t = threadIdx.x;
  int lane = t & 63, wid = t >> 6;
  int mb = blockIdx.x * 128, nb = blockIdx.y * 128;
  int wm = (wid >> 1) * 64, wn = (wid & 1) * 64;
  int l15 = lane & 15, lg = lane >> 4;
  int srow = lane >> 2;
  int schunk = (lane & 3) ^ (srow & 3);
  const u16* Ag = Ap + (size_t)(mb + wid * 32 + srow) * K + schunk * 8;
  const u16* Bg = Bt + (size_t)(nb + wid * 32 + srow) * K + schunk * 8;
  u16* Alw0 = &Al[(wid * 32) * 32];
  u16* Alw1 = &Al[(wid * 32 + 16) * 32];
  u16* Blw0 = &Bl[(wid * 32) * 32];
  u16* Blw1 = &Bl[(wid * 32 + 16) * 32];
  int ca = (lg ^ (l15 & 3)) * 8;
  f32x4 acc[4][4] = {};
  for (int kt = 0; kt < K; kt += 32) {
    gload16(Ag + kt, Alw0);
    gload16(Ag + kt + (size_t)16 * K, Alw1);
    gload16(Bg + kt, Blw0);
    gload16(Bg + kt + (size_t)16 * K, Blw1);
    __syncthreads();
    short8 af[4], bfv[4];
    #pragma unroll
    for (int mf = 0; mf < 4; mf++)
      af[mf] = *(const short8*)&Al[(wm + mf * 16 + l15) * 32 + ca];
    #pragma unroll
    for (int nf = 0; nf < 4; nf++)
      bfv[nf] = *(const short8*)&Bl[(wn + nf * 16 + l15) * 32 + ca];
    #pragma unroll
    for (int mf = 0; mf < 4; mf++)
      #pragma unroll
      for (int nf = 0; nf < 4; nf++)
        acc[mf][nf] = __builtin_amdgcn_mfma_f32_16x16x32_bf16(af[mf], bfv[nf], acc[mf][nf], 0, 0, 0);
    __syncthreads();
  }
  float bv[4];
  #pragma unroll
  for (int nf = 0; nf < 4; nf++) bv[nf] = bias[nb + wn + nf * 16 + l15];
  #pragma unroll
  for (int mf = 0; mf < 4; mf++) {
    #pragma unroll
    for (int r = 0; r < 4; r++) {
      int m = mb + wm + mf * 16 + lg * 4 + r;
      #pragma unroll
      for (int nf = 0; nf < 4; nf++) {
        int n = nb + wn + nf * 16 + l15;
        float rv = b2f(resid[(size_t)m * N + n]);
        Cp[(size_t)m * N + n] = acc[mf][nf][r] + bv[nf] + rv;
      }
    }
  }
}

// ---------------- flash attention, 2 Q-tiles per block, XCD-local grid ----------------
// grid: (B*H, S/128): all 16 qt-blocks of one (b,h) land on XCD bh%8 and share
// its L2 copy of K/V. 4 waves; each wave owns q rows {qt*128+wid*16+l15} and
// {+64}. K/V tile staged once per iteration serves both Q-sets. Single-buffer
// LDS (best measured vs dbuf: occupancy > barrier savings). Double-swapped MFMA,
// fixed-bound softmax (exp2 domain), LUT mask post-exp, incremental pointers.
__global__ __launch_bounds__(256) void attn_kernel(const u16* __restrict__ qh,
    const u16* __restrict__ kh, const u16* __restrict__ vt,
    const u64* __restrict__ mp, u16* __restrict__ outp) {
  __shared__ u16 Kl[64 * 64];
  __shared__ u16 Vl[64 * 64];
  __shared__ u64 lutq[16];
  int t = threadIdx.x, lane = t & 63, wid = t >> 6;
  int bh = blockIdx.x, b = bh >> 4, h = bh & 15;
  int qt = blockIdx.y;
  int l15 = lane & 15, lg = lane >> 4;

  if (t < 16) {
    u32 n = t;
    u32 w0 = ((n & 1) ? 0u : 0xFFFFu) | ((n & 2) ? 0u : 0xFFFF0000u);
    u32 w1 = ((n & 4) ? 0u : 0xFFFFu) | ((n & 8) ? 0u : 0xFFFF0000u);
    lutq[n] = (u64)w0 | ((u64)w1 << 32);
  }

  int qrow0 = qt * 128 + wid * 16 + l15;
  int qrow1 = qrow0 + 64;
  const u16* qbase0 = qh + ((size_t)(b * SS + qrow0)) * EE + h * DD;
  const u16* qbase1 = qh + ((size_t)(b * SS + qrow1)) * EE + h * DD;
  short8 qa0 = *(const short8*)(qbase0 + lg * 8);
  short8 qa1 = *(const short8*)(qbase0 + 32 + lg * 8);
  short8 qb0 = *(const short8*)(qbase1 + lg * 8);
  short8 qb1 = *(const short8*)(qbase1 + 32 + lg * 8);
  const u64* mrow0 = mp + (size_t)(b * SS + qrow0) * (SS / 64);
  const u64* mrow1 = mp + (size_t)(b * SS + qrow1) * (SS / 64);

  bf16x4 onesv;
  #pragma unroll
  for (int i = 0; i < 4; i++) onesv[i] = (short)0x3F80;  // bf16 1.0

  int r0 = wid * 16 + (lane >> 3);
  int r1 = r0 + 8;
  int cc = lane & 7;
  int wk0 = r0 * 64 + ((cc ^ (r0 & 7)) * 8);
  int wk1 = r1 * 64 + ((cc ^ (r1 & 7)) * 8);
  const u16* kgb = kh + ((size_t)b * SS) * EE + h * DD;
  const u16* vgb = vt + ((size_t)bh * DD) * SS;

  int ck0 = (lg ^ (l15 & 7)) * 8;
  int ck1 = ((4 + lg) ^ (l15 & 7)) * 8;
  int vbase0 = l15 * 64 + ((lg >> 1) ^ (l15 & 7)) * 8 + (lg & 1) * 4;

  f32x4 Oa[4] = {}, Ob[4] = {};
  f32x4 asuma = {}, asumb = {};
  constexpr int NT = SS / 64;

  // preload tile 0; incremental pointers start at tile 1
  uint4 sk0 = *(const uint4*)(kgb + (size_t)r0 * EE + cc * 8);
  uint4 sk1 = *(const uint4*)(kgb + (size_t)r1 * EE + cc * 8);
  uint4 sv0 = *(const uint4*)(vgb + (size_t)r0 * SS + cc * 8);
  uint4 sv1 = *(const uint4*)(vgb + (size_t)r1 * SS + cc * 8);
  const u16* kp0 = kgb + (size_t)(64 + r0) * EE + cc * 8;
  const u16* kp1 = kgb + (size_t)(64 + r1) * EE + cc * 8;
  const u16* vp0 = vgb + (size_t)r0 * SS + 64 + cc * 8;
  const u16* vp1 = vgb + (size_t)r1 * SS + 64 + cc * 8;
  u64 mwa = mrow0[0];
  u64 mwb = mrow1[0];

  for (int kt = 0; kt < NT; ++kt) {
    *(uint4*)&Kl[wk0] = sk0;
    *(uint4*)&Kl[wk1] = sk1;
    *(uint4*)&Vl[wk0] = sv0;
    *(uint4*)&Vl[wk1] = sv1;
    __syncthreads();

    // prefetch next tile (last iteration reads 1 past — in-bounds ws, discarded)
    sk0 = *(const uint4*)kp0; kp0 += 64 * EE;
    sk1 = *(const uint4*)kp1; kp1 += 64 * EE;
    sv0 = *(const uint4*)vp0; vp0 += 64;
    sv1 = *(const uint4*)vp1; vp1 += 64;
    u64 mwan = mrow0[kt + 1];
    u64 mwbn = mrow1[kt + 1];

    // mask nibble decode + LUT pattern reads, both q-sets
    u32 mloa = (u32)(mwa >> (lg * 4));
    u32 mhia = (u32)(mwa >> 32 >> (lg * 4));
    u32 mlob = (u32)(mwb >> (lg * 4));
    u32 mhib = (u32)(mwb >> 32 >> (lg * 4));
    uint2 pata[4], patb[4];
    pata[0] = *(uint2*)&lutq[mloa & 15u];
    pata[1] = *(uint2*)&lutq[(mloa >> 16) & 15u];
    pata[2] = *(uint2*)&lutq[mhia & 15u];
    pata[3] = *(uint2*)&lutq[(mhia >> 16) & 15u];
    patb[0] = *(uint2*)&lutq[mlob & 15u];
    patb[1] = *(uint2*)&lutq[(mlob >> 16) & 15u];
    patb[2] = *(uint2*)&lutq[mhib & 15u];
    patb[3] = *(uint2*)&lutq[(mhib >> 16) & 15u];

    // QK^T swapped, both q-sets off the SAME K fragments
    f32x4 sca[4], scb[4];
    #pragma unroll
    for (int nf = 0; nf < 4; nf++) {
      int row = nf * 16 + l15;
      short8 k0 = *(const short8*)&Kl[row * 64 + ck0];
      short8 k1 = *(const short8*)&Kl[row * 64 + ck1];
      f32x4 za = {}, zb = {};
      za = __builtin_amdgcn_mfma_f32_16x16x32_bf16(k0, qa0, za, 0, 0, 0);
      za = __builtin_amdgcn_mfma_f32_16x16x32_bf16(k1, qa1, za, 0, 0, 0);
      zb = __builtin_amdgcn_mfma_f32_16x16x32_bf16(k0, qb0, zb, 0, 0, 0);
      zb = __builtin_amdgcn_mfma_f32_16x16x32_bf16(k1, qb1, zb, 0, 0, 0);
      sca[nf] = za;
      scb[nf] = zb;
    }

    // P = exp2(sc)
    #pragma unroll
    for (int nf = 0; nf < 4; nf++) {
      #pragma unroll
      for (int r = 0; r < 4; r++) {
        sca[nf][r] = fexp2(sca[nf][r]);
        scb[nf][r] = fexp2(scb[nf][r]);
      }
    }

    // pack + mask-AND + asum + PV, sharing V fragments between q-sets
    #pragma unroll
    for (int nf = 0; nf < 4; nf++) {
      bf16x4 pba, pbb;
      ((u32*)&pba)[0] = cvtpk(sca[nf][0], sca[nf][1]) & pata[nf].x;
      ((u32*)&pba)[1] = cvtpk(sca[nf][2], sca[nf][3]) & pata[nf].y;
      ((u32*)&pbb)[0] = cvtpk(scb[nf][0], scb[nf][1]) & patb[nf].x;
      ((u32*)&pbb)[1] = cvtpk(scb[nf][2], scb[nf][3]) & patb[nf].y;
      asuma = mfma16(onesv, pba, asuma);
      asumb = mfma16(onesv, pbb, asumb);
      int vo = vbase0 ^ (nf * 16);
      #pragma unroll
      for (int df = 0; df < 4; df++) {
        bf16x4 vf = *(const bf16x4*)&Vl[vo + df * 1024];
        Oa[df] = mfma16(vf, pba, Oa[df]);
        Ob[df] = mfma16(vf, pbb, Ob[df]);
      }
    }
    mwa = mwan;
    mwb = mwbn;
    __syncthreads();
  }

  float inva = 1.0f / asuma[0];
  float invb = 1.0f / asumb[0];
  u16* ob0 = outp + ((size_t)(b * SS + qrow0)) * EE + h * DD + lg * 4;
  u16* ob1 = outp + ((size_t)(b * SS + qrow1)) * EE + h * DD + lg * 4;
  #pragma unroll
  for (int df = 0; df < 4; df++) {
    ushort4 pka, pkb;
    pka.x = f2b(Oa[df][0] * inva);
    pka.y = f2b(Oa[df][1] * inva);
    pka.z = f2b(Oa[df][2] * inva);
    pka.w = f2b(Oa[df][3] * inva);
    pkb.x = f2b(Ob[df][0] * invb);
    pkb.y = f2b(Ob[df][1] * invb);
    pkb.z = f2b(Ob[df][2] * invb);
    pkb.w = f2b(Ob[df][3] * invb);
    *(ushort4*)(ob0 + df * 16) = pka;
    *(ushort4*)(ob1 + df * 16) = pkb;
  }
}

extern "C" void kernel_launch(void* const* d_in, const int* in_sizes, int n_in,
                              void* d_out, int out_size, void* d_ws, size_t ws_size,
                              hipStream_t stream) {
  (void)in_sizes; (void)n_in; (void)out_size;
  const float* q    = (const float*)d_in[0];
  const float* k    = (const float*)d_in[1];
  const float* v    = (const float*)d_in[2];
  const int*   mask = (const int*)d_in[3];
  const float* W1   = (const float*)d_in[4];
  const float* b1   = (const float*)d_in[5];
  const float* W2   = (const float*)d_in[6];
  const float* b2   = (const float*)d_in[7];
  const float* W3   = (const float*)d_in[8];
  const float* b3   = (const float*)d_in[9];
  const float* W4   = (const float*)d_in[10];
  const float* b4   = (const float*)d_in[11];
  const float* gamma = (const float*)d_in[12];
  const float* beta  = (const float*)d_in[13];
  float* out = (float*)d_out;
  char* ws = (char*)d_ws;
  const size_t MB = 1024 * 1024;
  u16* qh  = (u16*)(ws + 0 * MB);
  u16* kh  = (u16*)(ws + 16 * MB);
  u16* vt  = (u16*)(ws + 32 * MB);   // early (fallback): kbf; later: V^T
  u16* ao  = (u16*)(ws + 48 * MB);   // early: qbf; later: attn out
  u16* vn  = (u16*)(ws + 64 * MB);
  u16* W1t = (u16*)(ws + 80 * MB);
  u16* W2t = (u16*)(ws + 82 * MB);
  u16* W3t = (u16*)(ws + 84 * MB);
  u16* W4t = (u16*)(ws + 86 * MB);
  u64* mp  = (u64*)(ws + 88 * MB);
  float* tmp = (float*)(ws + 0 * MB);  // overlays qh+kh (dead by then)
  u16* qbf = ao;

  bool ws_ok = ws_size >= 107 * MB;
  u16* kbf = ws_ok ? (u16*)(ws + 90 * MB) : vt;

  pre_kernel<<<36864, 256, 0, stream>>>(v, gamma, beta, vn, q, qbf, k, kbf,
                                        mask, mp, W1, W2, W3, W4,
                                        W1t, W2t, W3t, W4t);
  if (ws_ok) {
    gemm_proj<<<dim3(192, 8), 256, 0, stream>>>(qbf, kbf, vn, W1t, W2t, W3t,
                                                b1, b2, b3, qh, kh, vt, 0);
  } else {
    gemm_proj<<<dim3(128, 8), 256, 0, stream>>>(qbf, kbf, vn, W1t, W2t, W3t,
                                                b1, b2, b3, qh, kh, vt, 0);
    gemm_proj<<<dim3(64, 8), 256, 0, stream>>>(qbf, kbf, vn, W1t, W2t, W3t,
                                               b1, b2, b3, qh, kh, vt, 128);
  }
  attn_kernel<<<dim3(64, 16), 256, 0, stream>>>(qh, kh, vt, mp, ao);
  gemm_out<<<dim3(64, 8), 256, 0, stream>>>(ao, W4t, b4, vn, tmp);
  ln_kernel<false><<<8192, 256, 0, stream>>>(tmp, gamma, beta, out);
}

// Round 16
// 269.446 us; speedup vs baseline: 1.0490x; 1.0088x over previous
//
#include <hip/hip_runtime.h>

typedef unsigned short u16;
typedef unsigned int u32;
typedef unsigned long long u64;
typedef float f32x4 __attribute__((ext_vector_type(4)));
typedef short short8 __attribute__((ext_vector_type(8)));
typedef short bf16x4 __attribute__((ext_vector_type(4)));

#define BB 4
#define SS 2048
#define EE 1024
#define HH 16
#define DD 64
#define EPSV 1e-5f
#define LOG2E 1.4426950408889634f

__device__ __forceinline__ u16 f2b(float x) {
  u32 u = __float_as_uint(x);
  u32 r = (u + 0x7fffu + ((u >> 16) & 1u)) >> 16;
  return (u16)r;
}
__device__ __forceinline__ float b2f(u16 u) {
  return __uint_as_float(((u32)u) << 16);
}
__device__ __forceinline__ u32 cvtpk(float lo, float hi) {
  u32 r;
  asm("v_cvt_pk_bf16_f32 %0, %1, %2" : "=v"(r) : "v"(lo), "v"(hi));
  return r;
}
// raw v_exp_f32 (2^x) — avoids the __ocml_exp2_f32 libm call bloat
__device__ __forceinline__ float fexp2(float x) {
  float r;
  asm("v_exp_f32 %0, %1" : "=v"(r) : "v"(x));
  return r;
}
__device__ __forceinline__ void gload16(const void* g, void* l) {
  __builtin_amdgcn_global_load_lds(
      (const __attribute__((address_space(1))) u32*)g,
      (__attribute__((address_space(3))) u32*)l, 16, 0, 0);
}
// 16x16x16 bf16 MFMA with builtin-name fallback chain
__device__ __forceinline__ f32x4 mfma16(bf16x4 a, bf16x4 b, f32x4 c) {
#if __has_builtin(__builtin_amdgcn_mfma_f32_16x16x16_bf16)
  return __builtin_amdgcn_mfma_f32_16x16x16_bf16(a, b, c, 0, 0, 0);
#elif __has_builtin(__builtin_amdgcn_mfma_f32_16x16x16bf16_1k)
  return __builtin_amdgcn_mfma_f32_16x16x16bf16_1k(a, b, c, 0, 0, 0);
#else
  asm("v_mfma_f32_16x16x16_bf16 %0, %1, %2, %3"
      : "=v"(c) : "v"(a), "v"(b), "v"(c));
  return c;
#endif
}

// ---------------- LayerNorm: 1 block per row of 1024 fp32 ----------------
template<bool OUT_BF16>
__global__ __launch_bounds__(256) void ln_kernel(const float* __restrict__ x,
    const float* __restrict__ gamma, const float* __restrict__ beta,
    void* __restrict__ outp) {
  int row = blockIdx.x;
  int t = threadIdx.x;
  const float4* xr = (const float4*)(x + (size_t)row * EE);
  float4 v = xr[t];
  float s = v.x + v.y + v.z + v.w;
  #pragma unroll
  for (int o = 1; o < 64; o <<= 1) s += __shfl_xor(s, o);
  __shared__ float red[8];
  int wid = t >> 6;
  if ((t & 63) == 0) red[wid] = s;
  __syncthreads();
  float mean = (red[0] + red[1] + red[2] + red[3]) * (1.0f / EE);
  float d0 = v.x - mean, d1 = v.y - mean, d2 = v.z - mean, d3 = v.w - mean;
  float sq = d0 * d0 + d1 * d1 + d2 * d2 + d3 * d3;
  #pragma unroll
  for (int o = 1; o < 64; o <<= 1) sq += __shfl_xor(sq, o);
  if ((t & 63) == 0) red[4 + wid] = sq;
  __syncthreads();
  float var = (red[4] + red[5] + red[6] + red[7]) * (1.0f / EE);
  float rstd = rsqrtf(var + EPSV);
  float4 g = ((const float4*)gamma)[t];
  float4 be = ((const float4*)beta)[t];
  float o0 = d0 * rstd * g.x + be.x;
  float o1 = d1 * rstd * g.y + be.y;
  float o2 = d2 * rstd * g.z + be.z;
  float o3 = d3 * rstd * g.w + be.w;
  if (OUT_BF16) {
    ushort4 pk;
    pk.x = f2b(o0); pk.y = f2b(o1); pk.z = f2b(o2); pk.w = f2b(o3);
    *(ushort4*)((u16*)outp + (size_t)row * EE + t * 4) = pk;
  } else {
    ((float4*)((float*)outp + (size_t)row * EE))[t] = make_float4(o0, o1, o2, o3);
  }
}

// ---- fused preprocessing: LN(v), conv q/k, maskpack, wtrans x4; one launch ----
__global__ __launch_bounds__(256) void pre_kernel(
    const float* __restrict__ v, const float* __restrict__ gamma,
    const float* __restrict__ beta, u16* __restrict__ vn,
    const float* __restrict__ q, u16* __restrict__ qbf,
    const float* __restrict__ k, u16* __restrict__ kbf,
    const int* __restrict__ mask, u64* __restrict__ mp,
    const float* __restrict__ W1, const float* __restrict__ W2,
    const float* __restrict__ W3, const float* __restrict__ W4,
    u16* __restrict__ W1t, u16* __restrict__ W2t,
    u16* __restrict__ W3t, u16* __restrict__ W4t) {
  __shared__ float tile[32][33];
  __shared__ float red[8];
  int idx = blockIdx.x;
  int t = threadIdx.x;
  if (idx < 8192) {
    int row = idx;
    float4 vv = ((const float4*)(v + (size_t)row * EE))[t];
    float s = vv.x + vv.y + vv.z + vv.w;
    #pragma unroll
    for (int o = 1; o < 64; o <<= 1) s += __shfl_xor(s, o);
    int wid = t >> 6;
    if ((t & 63) == 0) red[wid] = s;
    __syncthreads();
    float mean = (red[0] + red[1] + red[2] + red[3]) * (1.0f / EE);
    float d0 = vv.x - mean, d1 = vv.y - mean, d2 = vv.z - mean, d3 = vv.w - mean;
    float sq = d0 * d0 + d1 * d1 + d2 * d2 + d3 * d3;
    #pragma unroll
    for (int o = 1; o < 64; o <<= 1) sq += __shfl_xor(sq, o);
    if ((t & 63) == 0) red[4 + wid] = sq;
    __syncthreads();
    float var = (red[4] + red[5] + red[6] + red[7]) * (1.0f / EE);
    float rstd = rsqrtf(var + EPSV);
    float4 g = ((const float4*)gamma)[t];
    float4 be = ((const float4*)beta)[t];
    ushort4 pk;
    pk.x = f2b(d0 * rstd * g.x + be.x);
    pk.y = f2b(d1 * rstd * g.y + be.y);
    pk.z = f2b(d2 * rstd * g.z + be.z);
    pk.w = f2b(d3 * rstd * g.w + be.w);
    *(ushort4*)(vn + (size_t)row * EE + t * 4) = pk;
  } else if (idx < 16384) {
    int i = idx - 8192;
    const float* x = (i >= 4096) ? k : q;
    u16* y = (i >= 4096) ? kbf : qbf;
    size_t off = ((size_t)(i & 4095) * 256 + t) * 8;
    float4 a = *(const float4*)(x + off);
    float4 c = *(const float4*)(x + off + 4);
    uint4 pk;
    pk.x = (u32)f2b(a.x) | ((u32)f2b(a.y) << 16);
    pk.y = (u32)f2b(a.z) | ((u32)f2b(a.w) << 16);
    pk.z = (u32)f2b(c.x) | ((u32)f2b(c.y) << 16);
    pk.w = (u32)f2b(c.z) | ((u32)f2b(c.w) << 16);
    *(uint4*)(y + off) = pk;
  } else if (idx < 32768) {
    int widx = idx - 16384;
    int wv = t >> 6, lane = t & 63;
    size_t base = (size_t)widx * 1024 + wv * 256;
    int v0 = mask[base + 0 * 64 + lane];
    int v1 = mask[base + 1 * 64 + lane];
    int v2 = mask[base + 2 * 64 + lane];
    int v3 = mask[base + 3 * 64 + lane];
    u64 b0 = __ballot(v0 != 0);
    u64 b1 = __ballot(v1 != 0);
    u64 b2 = __ballot(v2 != 0);
    u64 b3 = __ballot(v3 != 0);
    if (lane == 0) {
      u64* dst = &mp[base >> 6];
      dst[0] = b0; dst[1] = b1; dst[2] = b2; dst[3] = b3;
    }
  } else {
    int s = idx - 32768;
    int w = s >> 10, t2 = s & 1023;
    int kb = (t2 & 31) * 32, nb = (t2 >> 5) * 32;
    const float* W = (w == 0) ? W1 : (w == 1) ? W2 : (w == 2) ? W3 : W4;
    u16* Wt = (w == 0) ? W1t : (w == 1) ? W2t : (w == 2) ? W3t : W4t;
    int r = t >> 3, c = (t & 7) * 4;
    float4 vv = *(const float4*)&W[(size_t)(kb + r) * EE + nb + c];
    tile[r][c] = vv.x; tile[r][c + 1] = vv.y;
    tile[r][c + 2] = vv.z; tile[r][c + 3] = vv.w;
    __syncthreads();
    uint2 val;
    val.x = (u32)f2b(tile[c][r]) | ((u32)f2b(tile[c + 1][r]) << 16);
    val.y = (u32)f2b(tile[c + 2][r]) | ((u32)f2b(tile[c + 3][r]) << 16);
    *(uint2*)&Wt[(size_t)(nb + r) * EE + kb + c] = val;
  }
}

// ---------------- merged projection GEMM (q/k/v in one launch) ----------------
// XCD-local grid: launch (192, 8); panel id = blockIdx.x (so the 8 N-blocks of
// one A-panel have linear ids == panel (mod 8) -> same XCD L2 holds the panel).
__global__ __launch_bounds__(256) void gemm_proj(
    const u16* __restrict__ Aq, const u16* __restrict__ Ak,
    const u16* __restrict__ Av,
    const u16* __restrict__ W1t, const u16* __restrict__ W2t,
    const u16* __restrict__ W3t,
    const float* __restrict__ b1, const float* __restrict__ b2,
    const float* __restrict__ b3,
    u16* __restrict__ qh, u16* __restrict__ kh, u16* __restrict__ vt,
    int yoff) {
  constexpr int N = 1024, K = 1024;
  __shared__ u16 Al[128 * 32];
  __shared__ u16 Bl[128 * 32];
  int y = blockIdx.x + yoff;
  int sel = y >> 6, my = y & 63;
  const u16* Ap = (sel == 0) ? Aq : (sel == 1) ? Ak : Av;
  const u16* Bt = (sel == 0) ? W1t : (sel == 1) ? W2t : W3t;
  const float* bias = (sel == 0) ? b1 : (sel == 1) ? b2 : b3;
  u16* Cp = (sel == 0) ? qh : (sel == 1) ? kh : vt;
  float oscale = (sel == 0) ? LOG2E : 1.0f;

  int t = threadIdx.x;
  int lane = t & 63, wid = t >> 6;
  int mb = my * 128, nb = blockIdx.y * 128;
  int wm = (wid >> 1) * 64, wn = (wid & 1) * 64;
  int l15 = lane & 15, lg = lane >> 4;

  int srow = lane >> 2;
  int schunk = (lane & 3) ^ (srow & 3);
  const u16* Ag = Ap + (size_t)(mb + wid * 32 + srow) * K + schunk * 8;
  const u16* Bg = Bt + (size_t)(nb + wid * 32 + srow) * K + schunk * 8;
  u16* Alw0 = &Al[(wid * 32) * 32];
  u16* Alw1 = &Al[(wid * 32 + 16) * 32];
  u16* Blw0 = &Bl[(wid * 32) * 32];
  u16* Blw1 = &Bl[(wid * 32 + 16) * 32];
  int ca = (lg ^ (l15 & 3)) * 8;

  f32x4 acc[4][4] = {};
  for (int kt = 0; kt < K; kt += 32) {
    gload16(Ag + kt, Alw0);
    gload16(Ag + kt + (size_t)16 * K, Alw1);
    gload16(Bg + kt, Blw0);
    gload16(Bg + kt + (size_t)16 * K, Blw1);
    __syncthreads();
    short8 af[4], bfv[4];
    #pragma unroll
    for (int mf = 0; mf < 4; mf++)
      af[mf] = *(const short8*)&Al[(wm + mf * 16 + l15) * 32 + ca];
    #pragma unroll
    for (int nf = 0; nf < 4; nf++)
      bfv[nf] = *(const short8*)&Bl[(wn + nf * 16 + l15) * 32 + ca];
    #pragma unroll
    for (int mf = 0; mf < 4; mf++)
      #pragma unroll
      for (int nf = 0; nf < 4; nf++)
        acc[mf][nf] = __builtin_amdgcn_mfma_f32_16x16x32_bf16(af[mf], bfv[nf], acc[mf][nf], 0, 0, 0);
    __syncthreads();
  }
  float bv[4];
  #pragma unroll
  for (int nf = 0; nf < 4; nf++) bv[nf] = bias[nb + wn + nf * 16 + l15];
  if (sel == 2) {
    #pragma unroll
    for (int mf = 0; mf < 4; mf++) {
      int m0 = mb + wm + mf * 16 + lg * 4;
      int bq = m0 >> 11, s0 = m0 & 2047;
      #pragma unroll
      for (int nf = 0; nf < 4; nf++) {
        int n = nb + wn + nf * 16 + l15;
        int h = n >> 6, d = n & 63;
        ushort4 pk;
        pk.x = f2b(acc[mf][nf][0] + bv[nf]);
        pk.y = f2b(acc[mf][nf][1] + bv[nf]);
        pk.z = f2b(acc[mf][nf][2] + bv[nf]);
        pk.w = f2b(acc[mf][nf][3] + bv[nf]);
        *(ushort4*)&vt[((size_t)((bq * HH + h) * DD + d)) * SS + s0] = pk;
      }
    }
  } else {
    #pragma unroll
    for (int mf = 0; mf < 4; mf++) {
      #pragma unroll
      for (int r = 0; r < 4; r++) {
        int m = mb + wm + mf * 16 + lg * 4 + r;
        #pragma unroll
        for (int nf = 0; nf < 4; nf++) {
          int n = nb + wn + nf * 16 + l15;
          Cp[(size_t)m * N + n] = f2b((acc[mf][nf][r] + bv[nf]) * oscale);
        }
      }
    }
  }
}

// ---------------- output GEMM: fp32 C = A@W4t^T + b4 + residual ----------------
// XCD-local grid: launch (64, 8); panel id = blockIdx.x.
__global__ __launch_bounds__(256) void gemm_out(const u16* __restrict__ Ap,
    const u16* __restrict__ Bt, const float* __restrict__ bias,
    const u16* __restrict__ resid, float* __restrict__ Cp) {
  constexpr int N = 1024, K = 1024;
  __shared__ u16 Al[128 * 32];
  __shared__ u16 Bl[128 * 32];
  int t = threadIdx.x;
  int lane = t & 63, wid = t >> 6;
  int mb = blockIdx.x * 128, nb = blockIdx.y * 128;
  int wm = (wid >> 1) * 64, wn = (wid & 1) * 64;
  int l15 = lane & 15, lg = lane >> 4;
  int srow = lane >> 2;
  int schunk = (lane & 3) ^ (srow & 3);
  const u16* Ag = Ap + (size_t)(mb + wid * 32 + srow) * K + schunk * 8;
  const u16* Bg = Bt + (size_t)(nb + wid * 32 + srow) * K + schunk * 8;
  u16* Alw0 = &Al[(wid * 32) * 32];
  u16* Alw1 = &Al[(wid * 32 + 16) * 32];
  u16* Blw0 = &Bl[(wid * 32) * 32];
  u16* Blw1 = &Bl[(wid * 32 + 16) * 32];
  int ca = (lg ^ (l15 & 3)) * 8;
  f32x4 acc[4][4] = {};
  for (int kt = 0; kt < K; kt += 32) {
    gload16(Ag + kt, Alw0);
    gload16(Ag + kt + (size_t)16 * K, Alw1);
    gload16(Bg + kt, Blw0);
    gload16(Bg + kt + (size_t)16 * K, Blw1);
    __syncthreads();
    short8 af[4], bfv[4];
    #pragma unroll
    for (int mf = 0; mf < 4; mf++)
      af[mf] = *(const short8*)&Al[(wm + mf * 16 + l15) * 32 + ca];
    #pragma unroll
    for (int nf = 0; nf < 4; nf++)
      bfv[nf] = *(const short8*)&Bl[(wn + nf * 16 + l15) * 32 + ca];
    #pragma unroll
    for (int mf = 0; mf < 4; mf++)
      #pragma unroll
      for (int nf = 0; nf < 4; nf++)
        acc[mf][nf] = __builtin_amdgcn_mfma_f32_16x16x32_bf16(af[mf], bfv[nf], acc[mf][nf], 0, 0, 0);
    __syncthreads();
  }
  float bv[4];
  #pragma unroll
  for (int nf = 0; nf < 4; nf++) bv[nf] = bias[nb + wn + nf * 16 + l15];
  #pragma unroll
  for (int mf = 0; mf < 4; mf++) {
    #pragma unroll
    for (int r = 0; r < 4; r++) {
      int m = mb + wm + mf * 16 + lg * 4 + r;
      #pragma unroll
      for (int nf = 0; nf < 4; nf++) {
        int n = nb + wn + nf * 16 + l15;
        float rv = b2f(resid[(size_t)m * N + n]);
        Cp[(size_t)m * N + n] = acc[mf][nf][r] + bv[nf] + rv;
      }
    }
  }
}

// ---------------- flash attention, 2 Q-tiles per block, XCD-local grid ----------------
// grid: (B*H, S/128): all 16 qt-blocks of one (b,h) land on XCD bh%8 and share
// its L2 copy of K/V. 4 waves; each wave owns q rows {qt*128+wid*16+l15} and
// {+64}. K/V tile staged once per iteration serves both Q-sets. Single-buffer
// LDS (best measured vs dbuf). T5 setprio around MFMA clusters (independent
// blocks at different phases on each CU -> scheduler favors MFMA waves).
__global__ __launch_bounds__(256) void attn_kernel(const u16* __restrict__ qh,
    const u16* __restrict__ kh, const u16* __restrict__ vt,
    const u64* __restrict__ mp, u16* __restrict__ outp) {
  __shared__ u16 Kl[64 * 64];
  __shared__ u16 Vl[64 * 64];
  __shared__ u64 lutq[16];
  int t = threadIdx.x, lane = t & 63, wid = t >> 6;
  int bh = blockIdx.x, b = bh >> 4, h = bh & 15;
  int qt = blockIdx.y;
  int l15 = lane & 15, lg = lane >> 4;

  if (t < 16) {
    u32 n = t;
    u32 w0 = ((n & 1) ? 0u : 0xFFFFu) | ((n & 2) ? 0u : 0xFFFF0000u);
    u32 w1 = ((n & 4) ? 0u : 0xFFFFu) | ((n & 8) ? 0u : 0xFFFF0000u);
    lutq[n] = (u64)w0 | ((u64)w1 << 32);
  }

  int qrow0 = qt * 128 + wid * 16 + l15;
  int qrow1 = qrow0 + 64;
  const u16* qbase0 = qh + ((size_t)(b * SS + qrow0)) * EE + h * DD;
  const u16* qbase1 = qh + ((size_t)(b * SS + qrow1)) * EE + h * DD;
  short8 qa0 = *(const short8*)(qbase0 + lg * 8);
  short8 qa1 = *(const short8*)(qbase0 + 32 + lg * 8);
  short8 qb0 = *(const short8*)(qbase1 + lg * 8);
  short8 qb1 = *(const short8*)(qbase1 + 32 + lg * 8);
  const u64* mrow0 = mp + (size_t)(b * SS + qrow0) * (SS / 64);
  const u64* mrow1 = mp + (size_t)(b * SS + qrow1) * (SS / 64);

  bf16x4 onesv;
  #pragma unroll
  for (int i = 0; i < 4; i++) onesv[i] = (short)0x3F80;  // bf16 1.0

  int r0 = wid * 16 + (lane >> 3);
  int r1 = r0 + 8;
  int cc = lane & 7;
  int wk0 = r0 * 64 + ((cc ^ (r0 & 7)) * 8);
  int wk1 = r1 * 64 + ((cc ^ (r1 & 7)) * 8);
  const u16* kgb = kh + ((size_t)b * SS) * EE + h * DD;
  const u16* vgb = vt + ((size_t)bh * DD) * SS;

  int ck0 = (lg ^ (l15 & 7)) * 8;
  int ck1 = ((4 + lg) ^ (l15 & 7)) * 8;
  int vbase0 = l15 * 64 + ((lg >> 1) ^ (l15 & 7)) * 8 + (lg & 1) * 4;

  f32x4 Oa[4] = {}, Ob[4] = {};
  f32x4 asuma = {}, asumb = {};
  constexpr int NT = SS / 64;

  // preload tile 0; incremental pointers start at tile 1
  uint4 sk0 = *(const uint4*)(kgb + (size_t)r0 * EE + cc * 8);
  uint4 sk1 = *(const uint4*)(kgb + (size_t)r1 * EE + cc * 8);
  uint4 sv0 = *(const uint4*)(vgb + (size_t)r0 * SS + cc * 8);
  uint4 sv1 = *(const uint4*)(vgb + (size_t)r1 * SS + cc * 8);
  const u16* kp0 = kgb + (size_t)(64 + r0) * EE + cc * 8;
  const u16* kp1 = kgb + (size_t)(64 + r1) * EE + cc * 8;
  const u16* vp0 = vgb + (size_t)r0 * SS + 64 + cc * 8;
  const u16* vp1 = vgb + (size_t)r1 * SS + 64 + cc * 8;
  u64 mwa = mrow0[0];
  u64 mwb = mrow1[0];

  for (int kt = 0; kt < NT; ++kt) {
    *(uint4*)&Kl[wk0] = sk0;
    *(uint4*)&Kl[wk1] = sk1;
    *(uint4*)&Vl[wk0] = sv0;
    *(uint4*)&Vl[wk1] = sv1;
    __syncthreads();

    // prefetch next tile (last iteration reads 1 past — in-bounds ws, discarded)
    sk0 = *(const uint4*)kp0; kp0 += 64 * EE;
    sk1 = *(const uint4*)kp1; kp1 += 64 * EE;
    sv0 = *(const uint4*)vp0; vp0 += 64;
    sv1 = *(const uint4*)vp1; vp1 += 64;
    u64 mwan = mrow0[kt + 1];
    u64 mwbn = mrow1[kt + 1];

    // mask nibble decode + LUT pattern reads, both q-sets
    u32 mloa = (u32)(mwa >> (lg * 4));
    u32 mhia = (u32)(mwa >> 32 >> (lg * 4));
    u32 mlob = (u32)(mwb >> (lg * 4));
    u32 mhib = (u32)(mwb >> 32 >> (lg * 4));
    uint2 pata[4], patb[4];
    pata[0] = *(uint2*)&lutq[mloa & 15u];
    pata[1] = *(uint2*)&lutq[(mloa >> 16) & 15u];
    pata[2] = *(uint2*)&lutq[mhia & 15u];
    pata[3] = *(uint2*)&lutq[(mhia >> 16) & 15u];
    patb[0] = *(uint2*)&lutq[mlob & 15u];
    patb[1] = *(uint2*)&lutq[(mlob >> 16) & 15u];
    patb[2] = *(uint2*)&lutq[mhib & 15u];
    patb[3] = *(uint2*)&lutq[(mhib >> 16) & 15u];

    // QK^T swapped, both q-sets off the SAME K fragments (T5: boost MFMA waves)
    f32x4 sca[4], scb[4];
    __builtin_amdgcn_s_setprio(1);
    #pragma unroll
    for (int nf = 0; nf < 4; nf++) {
      int row = nf * 16 + l15;
      short8 k0 = *(const short8*)&Kl[row * 64 + ck0];
      short8 k1 = *(const short8*)&Kl[row * 64 + ck1];
      f32x4 za = {}, zb = {};
      za = __builtin_amdgcn_mfma_f32_16x16x32_bf16(k0, qa0, za, 0, 0, 0);
      za = __builtin_amdgcn_mfma_f32_16x16x32_bf16(k1, qa1, za, 0, 0, 0);
      zb = __builtin_amdgcn_mfma_f32_16x16x32_bf16(k0, qb0, zb, 0, 0, 0);
      zb = __builtin_amdgcn_mfma_f32_16x16x32_bf16(k1, qb1, zb, 0, 0, 0);
      sca[nf] = za;
      scb[nf] = zb;
    }
    __builtin_amdgcn_s_setprio(0);

    // P = exp2(sc)
    #pragma unroll
    for (int nf = 0; nf < 4; nf++) {
      #pragma unroll
      for (int r = 0; r < 4; r++) {
        sca[nf][r] = fexp2(sca[nf][r]);
        scb[nf][r] = fexp2(scb[nf][r]);
      }
    }

    // pack + mask-AND + asum + PV, sharing V fragments between q-sets
    __builtin_amdgcn_s_setprio(1);
    #pragma unroll
    for (int nf = 0; nf < 4; nf++) {
      bf16x4 pba, pbb;
      ((u32*)&pba)[0] = cvtpk(sca[nf][0], sca[nf][1]) & pata[nf].x;
      ((u32*)&pba)[1] = cvtpk(sca[nf][2], sca[nf][3]) & pata[nf].y;
      ((u32*)&pbb)[0] = cvtpk(scb[nf][0], scb[nf][1]) & patb[nf].x;
      ((u32*)&pbb)[1] = cvtpk(scb[nf][2], scb[nf][3]) & patb[nf].y;
      asuma = mfma16(onesv, pba, asuma);
      asumb = mfma16(onesv, pbb, asumb);
      int vo = vbase0 ^ (nf * 16);
      #pragma unroll
      for (int df = 0; df < 4; df++) {
        bf16x4 vf = *(const bf16x4*)&Vl[vo + df * 1024];
        Oa[df] = mfma16(vf, pba, Oa[df]);
        Ob[df] = mfma16(vf, pbb, Ob[df]);
      }
    }
    __builtin_amdgcn_s_setprio(0);
    mwa = mwan;
    mwb = mwbn;
    __syncthreads();
  }

  float inva = 1.0f / asuma[0];
  float invb = 1.0f / asumb[0];
  u16* ob0 = outp + ((size_t)(b * SS + qrow0)) * EE + h * DD + lg * 4;
  u16* ob1 = outp + ((size_t)(b * SS + qrow1)) * EE + h * DD + lg * 4;
  #pragma unroll
  for (int df = 0; df < 4; df++) {
    ushort4 pka, pkb;
    pka.x = f2b(Oa[df][0] * inva);
    pka.y = f2b(Oa[df][1] * inva);
    pka.z = f2b(Oa[df][2] * inva);
    pka.w = f2b(Oa[df][3] * inva);
    pkb.x = f2b(Ob[df][0] * invb);
    pkb.y = f2b(Ob[df][1] * invb);
    pkb.z = f2b(Ob[df][2] * invb);
    pkb.w = f2b(Ob[df][3] * invb);
    *(ushort4*)(ob0 + df * 16) = pka;
    *(ushort4*)(ob1 + df * 16) = pkb;
  }
}

extern "C" void kernel_launch(void* const* d_in, const int* in_sizes, int n_in,
                              void* d_out, int out_size, void* d_ws, size_t ws_size,
                              hipStream_t stream) {
  (void)in_sizes; (void)n_in; (void)out_size;
  const float* q    = (const float*)d_in[0];
  const float* k    = (const float*)d_in[1];
  const float* v    = (const float*)d_in[2];
  const int*   mask = (const int*)d_in[3];
  const float* W1   = (const float*)d_in[4];
  const float* b1   = (const float*)d_in[5];
  const float* W2   = (const float*)d_in[6];
  const float* b2   = (const float*)d_in[7];
  const float* W3   = (const float*)d_in[8];
  const float* b3   = (const float*)d_in[9];
  const float* W4   = (const float*)d_in[10];
  const float* b4   = (const float*)d_in[11];
  const float* gamma = (const float*)d_in[12];
  const float* beta  = (const float*)d_in[13];
  float* out = (float*)d_out;
  char* ws = (char*)d_ws;
  const size_t MB = 1024 * 1024;
  u16* qh  = (u16*)(ws + 0 * MB);
  u16* kh  = (u16*)(ws + 16 * MB);
  u16* vt  = (u16*)(ws + 32 * MB);   // early (fallback): kbf; later: V^T
  u16* ao  = (u16*)(ws + 48 * MB);   // early: qbf; later: attn out
  u16* vn  = (u16*)(ws + 64 * MB);
  u16* W1t = (u16*)(ws + 80 * MB);
  u16* W2t = (u16*)(ws + 82 * MB);
  u16* W3t = (u16*)(ws + 84 * MB);
  u16* W4t = (u16*)(ws + 86 * MB);
  u64* mp  = (u64*)(ws + 88 * MB);
  float* tmp = (float*)(ws + 0 * MB);  // overlays qh+kh (dead by then)
  u16* qbf = ao;

  bool ws_ok = ws_size >= 107 * MB;
  u16* kbf = ws_ok ? (u16*)(ws + 90 * MB) : vt;

  pre_kernel<<<36864, 256, 0, stream>>>(v, gamma, beta, vn, q, qbf, k, kbf,
                                        mask, mp, W1, W2, W3, W4,
                                        W1t, W2t, W3t, W4t);
  if (ws_ok) {
    gemm_proj<<<dim3(192, 8), 256, 0, stream>>>(qbf, kbf, vn, W1t, W2t, W3t,
                                                b1, b2, b3, qh, kh, vt, 0);
  } else {
    gemm_proj<<<dim3(128, 8), 256, 0, stream>>>(qbf, kbf, vn, W1t, W2t, W3t,
                                                b1, b2, b3, qh, kh, vt, 0);
    gemm_proj<<<dim3(64, 8), 256, 0, stream>>>(qbf, kbf, vn, W1t, W2t, W3t,
                                               b1, b2, b3, qh, kh, vt, 128);
  }
  attn_kernel<<<dim3(64, 16), 256, 0, stream>>>(qh, kh, vt, mp, ao);
  gemm_out<<<dim3(64, 8), 256, 0, stream>>>(ao, W4t, b4, vn, tmp);
  ln_kernel<false><<<8192, 256, 0, stream>>>(tmp, gamma, beta, out);
}